// Round 1
// baseline (405.241 us; speedup 1.0000x reference)
//
#include <hip/hip_runtime.h>
#include <cstddef>

#define K 64
#define D 768
#define D4 192   // D/4

__device__ __forceinline__ float d4f(float4 a, float4 b) {
  return a.x*b.x + a.y*b.y + a.z*b.z + a.w*b.w;
}
__device__ __forceinline__ float4 a4(float4 a, float4 b) {
  return make_float4(a.x+b.x, a.y+b.y, a.z+b.z, a.w+b.w);
}

// ---------------- Phase 1: per-chunk per-class sums + label histogram ----------------
// grid: NC*12 blocks (chunk, 64-wide d-slice), block: 256 threads (4 waves).
// Wave w accumulates vectors [w*C/4, (w+1)*C/4) of the chunk into its own LDS copy.
__global__ __launch_bounds__(256) void ph1_chunk_sums(
    const float* __restrict__ inputs, const int* __restrict__ labels,
    float* __restrict__ sums, int* __restrict__ cnts, int NC, int C)
{
  __shared__ float acc[4 * K * 64];   // 64 KB
  __shared__ int   hist[4 * K];       // 1 KB
  const int bi    = blockIdx.x;
  const int chunk = bi / 12, slice = bi % 12;
  const int w = threadIdx.x >> 6, l = threadIdx.x & 63;

  for (int e = threadIdx.x; e < 4 * K * 64; e += 256) acc[e] = 0.f;
  hist[threadIdx.x] = 0;   // 4*K == 256 exactly
  __syncthreads();

  const int C4 = C >> 2;
  const long long rbase = (long long)chunk * C + (long long)w * C4;
  float* accw = acc + w * (K * 64);
  for (int j = 0; j < C4; ++j) {
    long long r = rbase + j;
    int lab = labels[r];                              // wave-uniform
    float v = inputs[r * D + slice * 64 + l];         // coalesced 256B/wave
    accw[lab * 64 + l] += v;
    if (slice == 0 && l == 0) hist[w * K + lab]++;
  }
  __syncthreads();

  float* sp = sums + (long long)chunk * (K * D) + slice * 64;
  for (int e = threadIdx.x; e < K * 64; e += 256) {
    int k = e >> 6, dl = e & 63;
    float s = acc[0*K*64 + e] + acc[1*K*64 + e] + acc[2*K*64 + e] + acc[3*K*64 + e];
    sp[k * D + dl] = s;
  }
  if (slice == 0 && threadIdx.x < K) {
    cnts[chunk * K + threadIdx.x] =
        hist[0*K + threadIdx.x] + hist[1*K + threadIdx.x] +
        hist[2*K + threadIdx.x] + hist[3*K + threadIdx.x];
  }
}

// ---------------- Phase 2a: exclusive scan of sums over chunks (in place) ----------------
__global__ __launch_bounds__(256) void ph2a_scan_sums(float* __restrict__ sums, int NC)
{
  const int tid = blockIdx.x * 256 + threadIdx.x;   // [0, K*D)
  float run = 0.f;
  for (int m = 0; m < NC; ++m) {
    long long idx = (long long)m * (K * D) + tid;
    float t = sums[idx];
    sums[idx] = run;
    run += t;
  }
}

// ---------------- Phase 2b: exclusive scan of counts over chunks (in place) ----------------
__global__ void ph2b_scan_cnts(int* __restrict__ cnts, int NC)
{
  const int k = threadIdx.x;   // 64 threads
  int run = 0;
  for (int m = 0; m < NC; ++m) {
    int t = cnts[m * K + k];
    cnts[m * K + k] = run;
    run += t;
  }
}

// ---------------- Phase 3: per-chunk sequential scan, 4 classes per wave in registers ----
// grid: NC*4 blocks of 256 threads (4 waves). Wave (quad*4+w) owns classes [wid*4, wid*4+4).
// Lane l owns d in {4l..4l+3} + {256..} + {512..}  (3 float4s per row).
__global__ __launch_bounds__(256, 4) void ph3_scan(
    const float* __restrict__ inputs, const int* __restrict__ labels,
    const float* __restrict__ cavg, const float* __restrict__ base,
    const int* __restrict__ cnts, float* __restrict__ out, int NC, int C)
{
  const int bi = blockIdx.x;
  int chunk, quad;
  if (NC >= 8) {                       // cluster a chunk's 4 blocks onto one XCD
    int xcd = bi & 7, slot = bi >> 3;
    chunk = xcd * (NC >> 3) + (slot >> 2);
    quad  = slot & 3;
  } else {
    chunk = bi >> 2; quad = bi & 3;
  }
  const int w = threadIdx.x >> 6, l = threadIdx.x & 63;
  const int k0 = (quad * 4 + w) * 4;

  const int cb = chunk * K + k0;
  bool vg0 = (cnts[cb+0] == 0), vg1 = (cnts[cb+1] == 0);
  bool vg2 = (cnts[cb+2] == 0), vg3 = (cnts[cb+3] == 0);

  const float4* bp = (const float4*)base + (long long)chunk * (K * D4);
  const float4* cp = (const float4*)cavg;

  float4 A0[3], A1[3], A2[3], A3[3];
#pragma unroll
  for (int t = 0; t < 3; ++t) {
    int o = t * 64 + l;
    A0[t] = vg0 ? cp[(k0+0)*D4 + o] : bp[(k0+0)*D4 + o];
    A1[t] = vg1 ? cp[(k0+1)*D4 + o] : bp[(k0+1)*D4 + o];
    A2[t] = vg2 ? cp[(k0+2)*D4 + o] : bp[(k0+2)*D4 + o];
    A3[t] = vg3 ? cp[(k0+3)*D4 + o] : bp[(k0+3)*D4 + o];
  }
  // ||A||^2, replicated to all lanes via butterfly
  float n0 = 0.f, n1 = 0.f, n2 = 0.f, n3 = 0.f;
#pragma unroll
  for (int t = 0; t < 3; ++t) {
    n0 += d4f(A0[t], A0[t]); n1 += d4f(A1[t], A1[t]);
    n2 += d4f(A2[t], A2[t]); n3 += d4f(A3[t], A3[t]);
  }
#pragma unroll
  for (int m = 1; m <= 32; m <<= 1) {
    n0 += __shfl_xor(n0, m); n1 += __shfl_xor(n1, m);
    n2 += __shfl_xor(n2, m); n3 += __shfl_xor(n3, m);
  }

  const long long ibase = (long long)chunk * C;
  for (int j = 0; j < C; ++j) {
    const long long i = ibase + j;
    const int lab = labels[i];                       // wave-uniform
    const float4* vp = (const float4*)inputs + i * D4;
    float4 v0 = vp[l], v1 = vp[64 + l], v2 = vp[128 + l];

    float p0 = d4f(A0[0], v0) + d4f(A0[1], v1) + d4f(A0[2], v2);
    float p1 = d4f(A1[0], v0) + d4f(A1[1], v1) + d4f(A1[2], v2);
    float p2 = d4f(A2[0], v0) + d4f(A2[1], v1) + d4f(A2[2], v2);
    float p3 = d4f(A3[0], v0) + d4f(A3[1], v1) + d4f(A3[2], v2);
    float pv = d4f(v0, v0) + d4f(v1, v1) + d4f(v2, v2);
#pragma unroll
    for (int m = 1; m <= 32; m <<= 1) {
      p0 += __shfl_xor(p0, m); p1 += __shfl_xor(p1, m);
      p2 += __shfl_xor(p2, m); p3 += __shfl_xor(p3, m);
      pv += __shfl_xor(pv, m);
    }
    if (l < 4) {
      float ps = (l == 0) ? p0 : (l == 1) ? p1 : (l == 2) ? p2 : p3;
      float ns = (l == 0) ? n0 : (l == 1) ? n1 : (l == 2) ? n2 : n3;
      out[i * K + k0 + l] = ps * rsqrtf(fmaxf(ns * pv, 1e-30f));
    }
#define UPD(idx) do { \
      if (vg##idx) { A##idx[0]=v0; A##idx[1]=v1; A##idx[2]=v2; n##idx = pv; vg##idx = false; } \
      else { A##idx[0]=a4(A##idx[0],v0); A##idx[1]=a4(A##idx[1],v1); A##idx[2]=a4(A##idx[2],v2); \
             n##idx += 2.f * p##idx + pv; } } while (0)
    if      (lab == k0 + 0) UPD(0);
    else if (lab == k0 + 1) UPD(1);
    else if (lab == k0 + 2) UPD(2);
    else if (lab == k0 + 3) UPD(3);
#undef UPD
  }
}

extern "C" void kernel_launch(void* const* d_in, const int* in_sizes, int n_in,
                              void* d_out, int out_size, void* d_ws, size_t ws_size,
                              hipStream_t stream)
{
  const float* inputs = (const float*)d_in[0];
  const int*   labels = (const int*)d_in[1];
  const float* cavg   = (const float*)d_in[2];
  float* out = (float*)d_out;
  const int N = in_sizes[1];   // B*T = 32768

  // Pick largest power-of-2 chunk count that fits in workspace.
  int NC = 256;
  while (NC > 1) {
    size_t need = (size_t)NC * K * D * 4 + (size_t)NC * K * 4;
    if (need <= ws_size && (N % (NC * 4)) == 0) break;
    NC >>= 1;
  }
  const int C = N / NC;
  float* d_sums = (float*)d_ws;
  int*   d_cnts = (int*)((char*)d_ws + (size_t)NC * K * D * 4);

  hipLaunchKernelGGL(ph1_chunk_sums, dim3(NC * 12), dim3(256), 0, stream,
                     inputs, labels, d_sums, d_cnts, NC, C);
  hipLaunchKernelGGL(ph2a_scan_sums, dim3((K * D) / 256), dim3(256), 0, stream,
                     d_sums, NC);
  hipLaunchKernelGGL(ph2b_scan_cnts, dim3(1), dim3(64), 0, stream,
                     d_cnts, NC);
  hipLaunchKernelGGL(ph3_scan, dim3(NC * 4), dim3(256), 0, stream,
                     inputs, labels, cavg, d_sums, d_cnts, out, NC, C);
}

// Round 2
// 216.329 us; speedup vs baseline: 1.8733x; 1.8733x over previous
//
#include <hip/hip_runtime.h>
#include <cstddef>

#define K 64
#define D 768
#define D4 192   // D/4

__device__ __forceinline__ float d4f(float4 a, float4 b) {
  return a.x*b.x + a.y*b.y + a.z*b.z + a.w*b.w;
}
__device__ __forceinline__ float4 a4(float4 a, float4 b) {
  return make_float4(a.x+b.x, a.y+b.y, a.z+b.z, a.w+b.w);
}
__device__ __forceinline__ unsigned short f2bf(float x) {
  unsigned int u = __float_as_uint(x);
  unsigned int r = (u + 0x7FFFu + ((u >> 16) & 1u)) >> 16;
  return (unsigned short)r;
}

typedef __attribute__((ext_vector_type(8)))  short bf16x8;
typedef __attribute__((ext_vector_type(16))) float f32x16;

// =====================================================================
// FAST PATH (N=32768, NC=256, C=128)
// =====================================================================
#define NCF 256
#define CF  128

// ---- K1: cast inputs+cavg to bf16, compute ||v||^2 (f32 exact) ----
__global__ __launch_bounds__(256) void k1_cast(
    const float* __restrict__ inputs, const float* __restrict__ cavg,
    unsigned short* __restrict__ Vb, unsigned short* __restrict__ cavgb,
    float* __restrict__ pv, float* __restrict__ cn2, int N)
{
  int wave = blockIdx.x * 4 + (threadIdx.x >> 6);
  int l = threadIdx.x & 63;
  if (wave >= N + K) return;
  const float* src = (wave < N) ? inputs + (size_t)wave * D : cavg + (size_t)(wave - N) * D;
  unsigned short* dst = (wave < N) ? Vb + (size_t)wave * D : cavgb + (size_t)(wave - N) * D;
  float sq = 0.f;
#pragma unroll
  for (int t = 0; t < 3; ++t) {
    float4 v = ((const float4*)src)[t * 64 + l];
    sq += v.x*v.x + v.y*v.y + v.z*v.z + v.w*v.w;
    ushort4 o; o.x = f2bf(v.x); o.y = f2bf(v.y); o.z = f2bf(v.z); o.w = f2bf(v.w);
    ((ushort4*)dst)[t * 64 + l] = o;
  }
#pragma unroll
  for (int m = 1; m <= 32; m <<= 1) sq += __shfl_xor(sq, m);
  if (l == 0) { if (wave < N) pv[wave] = sq; else cn2[wave - N] = sq; }
}

// ---- K2: per-chunk per-class f32 sums + label histogram (cnts transposed [K][NC]) ----
__global__ __launch_bounds__(256) void k2_chunk_sums(
    const float* __restrict__ inputs, const int* __restrict__ labels,
    float* __restrict__ sums, int* __restrict__ cnts_t, int NC, int C)
{
  __shared__ float acc[4 * K * 64];
  __shared__ int   hist[4 * K];
  const int bi    = blockIdx.x;
  const int chunk = bi / 12, slice = bi % 12;
  const int w = threadIdx.x >> 6, l = threadIdx.x & 63;

  for (int e = threadIdx.x; e < 4 * K * 64; e += 256) acc[e] = 0.f;
  hist[threadIdx.x] = 0;
  __syncthreads();

  const int C4 = C >> 2;
  const long long rbase = (long long)chunk * C + (long long)w * C4;
  float* accw = acc + w * (K * 64);
  for (int j = 0; j < C4; ++j) {
    long long r = rbase + j;
    int lab = labels[r];
    float v = inputs[r * D + slice * 64 + l];
    accw[lab * 64 + l] += v;
    if (slice == 0 && l == 0) hist[w * K + lab]++;
  }
  __syncthreads();

  float* sp = sums + (long long)chunk * (K * D) + slice * 64;
  for (int e = threadIdx.x; e < K * 64; e += 256) {
    int k = e >> 6, dl = e & 63;
    float s = acc[0*K*64 + e] + acc[1*K*64 + e] + acc[2*K*64 + e] + acc[3*K*64 + e];
    sp[k * D + dl] = s;
  }
  if (slice == 0 && threadIdx.x < K) {
    cnts_t[threadIdx.x * NC + chunk] =
        hist[0*K + threadIdx.x] + hist[1*K + threadIdx.x] +
        hist[2*K + threadIdx.x] + hist[3*K + threadIdx.x];
  }
}

// ---- K2b: exclusive scan of transposed counts ----
__global__ void k2b_scan_cnts(int* __restrict__ cnts_t, int NC)
{
  int k = threadIdx.x;
  int run = 0;
  int* p = cnts_t + k * NC;
  for (int m = 0; m < NC; ++m) { int t = p[m]; p[m] = run; run += t; }
}

// ---- K3a: level-1 exclusive scan (16 chunks per group, in place) + group totals ----
__global__ __launch_bounds__(256) void k3a_scan_lo(float* __restrict__ sums, float* __restrict__ aux)
{
  int g   = blockIdx.x / 192;
  int col = (blockIdx.x % 192) * 256 + threadIdx.x;
  float run = 0.f;
  for (int m = g * 16; m < g * 16 + 16; ++m) {
    size_t idx = (size_t)m * (K * D) + col;
    float t = sums[idx]; sums[idx] = run; run += t;
  }
  aux[(size_t)g * (K * D) + col] = run;
}

// ---- K3b: scan group totals ----
__global__ __launch_bounds__(256) void k3b_scan_hi(float* __restrict__ aux)
{
  int col = blockIdx.x * 256 + threadIdx.x;
  float run = 0.f;
  for (int g = 0; g < 16; ++g) {
    size_t idx = (size_t)g * (K * D) + col;
    float t = aux[idx]; aux[idx] = run; run += t;
  }
}

// ---- K3c: base = sums + aux -> bf16 rows + exact f32 row norms ----
__global__ __launch_bounds__(256) void k3c_finalize(
    const float* __restrict__ sums, const float* __restrict__ aux,
    unsigned short* __restrict__ Sb16, float* __restrict__ bn2)
{
  int m = blockIdx.x >> 4, rb = blockIdx.x & 15;
  int w = threadIdx.x >> 6, l = threadIdx.x & 63;
  int k = rb * 4 + w;
  const float4* sp = (const float4*)(sums + ((size_t)m * K + k) * D);
  const float4* ap = (const float4*)(aux + (size_t)(m >> 4) * (K * D) + (size_t)k * D);
  unsigned short* dp = Sb16 + ((size_t)m * K + k) * D;
  float sq = 0.f;
#pragma unroll
  for (int t = 0; t < 3; ++t) {
    float4 s = sp[t * 64 + l], a = ap[t * 64 + l];
    float4 b = make_float4(s.x + a.x, s.y + a.y, s.z + a.z, s.w + a.w);
    sq += b.x*b.x + b.y*b.y + b.z*b.z + b.w*b.w;
    ushort4 o; o.x = f2bf(b.x); o.y = f2bf(b.y); o.z = f2bf(b.z); o.w = f2bf(b.w);
    ((ushort4*)dp)[t * 64 + l] = o;
  }
#pragma unroll
  for (int mm = 1; mm <= 32; mm <<= 1) sq += __shfl_xor(sq, mm);
  if (l == 0) bn2[m * K + k] = sq;
}

// ---- K4: per-chunk fused GEMMs ----
// dot[i][0:64]  = base·v_i + tril_strict(V V^T)·onehot   (class dot)
// dot[i][64:128]= cavg·v_i                                (unseen-class dot)
#define LDV 264   // 256 payload + 8 pad (bf16 elems), rows 16B-aligned
#define LDS2 136  // 128 payload + 8 pad for S / Mt
__global__ __launch_bounds__(256) void k4_gemm(
    const unsigned short* __restrict__ Vb, const unsigned short* __restrict__ Sb16,
    const unsigned short* __restrict__ cavgb, const int* __restrict__ labels,
    float* __restrict__ dotbuf)
{
  __shared__ unsigned short bufV[128 * LDV];
  __shared__ unsigned short bufB[128 * LDV];   // reused: ldsS[128*136] + Mt[64*136]
  const int m = blockIdx.x;
  const int tid = threadIdx.x, w = tid >> 6, l = tid & 63;
  const int r31 = l & 31, kh = l >> 5;

  f32x16 accP[4], accS[4];
#pragma unroll
  for (int t = 0; t < 4; ++t) { accP[t] = (f32x16){}; accS[t] = (f32x16){}; }

  for (int kd = 0; kd < 3; ++kd) {
    // stage V-tile and B'-tile (rows 0-63: scanned base, 64-127: cavg)
#pragma unroll 4
    for (int it = 0; it < 16; ++it) {
      int flat = it * 256 + tid;          // 4096 16B blocks
      int row = flat >> 5, c16 = flat & 31;
      const unsigned short* sv = Vb + ((size_t)(m * 128 + row)) * D + kd * 256 + c16 * 8;
      *(uint4*)(bufV + row * LDV + c16 * 8) = *(const uint4*)sv;
      const unsigned short* sb = (row < 64)
          ? Sb16 + ((size_t)m * K + row) * D + kd * 256 + c16 * 8
          : cavgb + (size_t)(row - 64) * D + kd * 256 + c16 * 8;
      *(uint4*)(bufB + row * LDV + c16 * 8) = *(const uint4*)sb;
    }
    __syncthreads();
#pragma unroll 4
    for (int kk = 0; kk < 16; ++kk) {
      bf16x8 av = *(const bf16x8*)(bufV + (32 * w + r31) * LDV + kk * 16 + kh * 8);
#pragma unroll
      for (int t = 0; t < 4; ++t) {
        bf16x8 bB = *(const bf16x8*)(bufB + (32 * t + r31) * LDV + kk * 16 + kh * 8);
        accP[t] = __builtin_amdgcn_mfma_f32_32x32x16_bf16(av, bB, accP[t], 0, 0, 0);
        bf16x8 bV = *(const bf16x8*)(bufV + (32 * t + r31) * LDV + kk * 16 + kh * 8);
        accS[t] = __builtin_amdgcn_mfma_f32_32x32x16_bf16(av, bV, accS[t], 0, 0, 0);
      }
    }
    __syncthreads();
  }

  // masked S -> bf16 LDS (strict lower: keep j < i), build one-hot Mt[k][j]
  unsigned short* ldsS = bufB;
  unsigned short* Mt   = bufB + 128 * LDS2;
#pragma unroll
  for (int t = 0; t < 4; ++t)
#pragma unroll
    for (int q = 0; q < 16; ++q) {
      int i = 32 * w + (q & 3) + 8 * (q >> 2) + 4 * kh;
      int j = 32 * t + r31;
      ldsS[i * LDS2 + j] = (j < i) ? f2bf(accS[t][q]) : (unsigned short)0;
    }
  {
    int j = tid & 127;
    int lab = labels[m * 128 + j];
    int kbase = (tid >> 7) * 32;
#pragma unroll 8
    for (int kk = 0; kk < 32; ++kk) {
      int k = kbase + kk;
      Mt[k * LDS2 + j] = (lab == k) ? (unsigned short)0x3F80 : (unsigned short)0;
    }
  }
  __syncthreads();

  // corr = tril_strict(S) @ onehot, accumulated into accP[0..1] (class cols)
#pragma unroll 2
  for (int kk = 0; kk < 8; ++kk) {
    bf16x8 aS = *(const bf16x8*)(ldsS + (32 * w + r31) * LDS2 + kk * 16 + kh * 8);
    bf16x8 b0 = *(const bf16x8*)(Mt + (r31) * LDS2 + kk * 16 + kh * 8);
    bf16x8 b1 = *(const bf16x8*)(Mt + (32 + r31) * LDS2 + kk * 16 + kh * 8);
    accP[0] = __builtin_amdgcn_mfma_f32_32x32x16_bf16(aS, b0, accP[0], 0, 0, 0);
    accP[1] = __builtin_amdgcn_mfma_f32_32x32x16_bf16(aS, b1, accP[1], 0, 0, 0);
  }

#pragma unroll
  for (int t = 0; t < 4; ++t)
#pragma unroll
    for (int q = 0; q < 16; ++q) {
      int i = 32 * w + (q & 3) + 8 * (q >> 2) + 4 * kh;
      int col = 32 * t + r31;
      dotbuf[((size_t)m * 128 + i) * 128 + col] = accP[t][q];
    }
}

// ---- K5: per-chunk norm-recurrence epilogue, lane = class ----
__global__ void k5_epilogue(
    const float* __restrict__ dotbuf, const float* __restrict__ pv,
    const int* __restrict__ labels, const int* __restrict__ cnts_t,
    const float* __restrict__ bn2, const float* __restrict__ cn2,
    float* __restrict__ out, int NC)
{
  int m = blockIdx.x;
  int k = threadIdx.x;          // 64 lanes = 64 classes
  int cnt = cnts_t[k * NC + m];
  float n = bn2[m * K + k];
  float cnk = cn2[k];
#pragma unroll 4
  for (int j = 0; j < CF; ++j) {
    int i = m * CF + j;
    float dS = dotbuf[(size_t)i * 128 + k];
    float dC = dotbuf[(size_t)i * 128 + 64 + k];
    float pvj = pv[i];
    int lab = labels[i];
    bool seen = cnt > 0;
    float val = seen ? dS : dC;
    float nn  = seen ? n : cnk;
    out[(size_t)i * K + k] = val * rsqrtf(fmaxf(nn * pvj, 1e-30f));
    if (k == lab) { n = seen ? (n + 2.f * dS + pvj) : pvj; cnt++; }
  }
}

// =====================================================================
// FALLBACK PATH — round-1 pipeline, verbatim (known-correct)
// =====================================================================
__global__ __launch_bounds__(256) void ph1_chunk_sums(
    const float* __restrict__ inputs, const int* __restrict__ labels,
    float* __restrict__ sums, int* __restrict__ cnts, int NC, int C)
{
  __shared__ float acc[4 * K * 64];
  __shared__ int   hist[4 * K];
  const int bi    = blockIdx.x;
  const int chunk = bi / 12, slice = bi % 12;
  const int w = threadIdx.x >> 6, l = threadIdx.x & 63;

  for (int e = threadIdx.x; e < 4 * K * 64; e += 256) acc[e] = 0.f;
  hist[threadIdx.x] = 0;
  __syncthreads();

  const int C4 = C >> 2;
  const long long rbase = (long long)chunk * C + (long long)w * C4;
  float* accw = acc + w * (K * 64);
  for (int j = 0; j < C4; ++j) {
    long long r = rbase + j;
    int lab = labels[r];
    float v = inputs[r * D + slice * 64 + l];
    accw[lab * 64 + l] += v;
    if (slice == 0 && l == 0) hist[w * K + lab]++;
  }
  __syncthreads();

  float* sp = sums + (long long)chunk * (K * D) + slice * 64;
  for (int e = threadIdx.x; e < K * 64; e += 256) {
    int k = e >> 6, dl = e & 63;
    float s = acc[0*K*64 + e] + acc[1*K*64 + e] + acc[2*K*64 + e] + acc[3*K*64 + e];
    sp[k * D + dl] = s;
  }
  if (slice == 0 && threadIdx.x < K) {
    cnts[chunk * K + threadIdx.x] =
        hist[0*K + threadIdx.x] + hist[1*K + threadIdx.x] +
        hist[2*K + threadIdx.x] + hist[3*K + threadIdx.x];
  }
}

__global__ __launch_bounds__(256) void ph2a_scan_sums(float* __restrict__ sums, int NC)
{
  const int tid = blockIdx.x * 256 + threadIdx.x;
  float run = 0.f;
  for (int m = 0; m < NC; ++m) {
    long long idx = (long long)m * (K * D) + tid;
    float t = sums[idx];
    sums[idx] = run;
    run += t;
  }
}

__global__ void ph2b_scan_cnts(int* __restrict__ cnts, int NC)
{
  const int k = threadIdx.x;
  int run = 0;
  for (int m = 0; m < NC; ++m) {
    int t = cnts[m * K + k];
    cnts[m * K + k] = run;
    run += t;
  }
}

__global__ __launch_bounds__(256, 4) void ph3_scan(
    const float* __restrict__ inputs, const int* __restrict__ labels,
    const float* __restrict__ cavg, const float* __restrict__ base,
    const int* __restrict__ cnts, float* __restrict__ out, int NC, int C)
{
  const int bi = blockIdx.x;
  int chunk, quad;
  if (NC >= 8) {
    int xcd = bi & 7, slot = bi >> 3;
    chunk = xcd * (NC >> 3) + (slot >> 2);
    quad  = slot & 3;
  } else {
    chunk = bi >> 2; quad = bi & 3;
  }
  const int w = threadIdx.x >> 6, l = threadIdx.x & 63;
  const int k0 = (quad * 4 + w) * 4;

  const int cb = chunk * K + k0;
  bool vg0 = (cnts[cb+0] == 0), vg1 = (cnts[cb+1] == 0);
  bool vg2 = (cnts[cb+2] == 0), vg3 = (cnts[cb+3] == 0);

  const float4* bp = (const float4*)base + (long long)chunk * (K * D4);
  const float4* cp = (const float4*)cavg;

  float4 A0[3], A1[3], A2[3], A3[3];
#pragma unroll
  for (int t = 0; t < 3; ++t) {
    int o = t * 64 + l;
    A0[t] = vg0 ? cp[(k0+0)*D4 + o] : bp[(k0+0)*D4 + o];
    A1[t] = vg1 ? cp[(k0+1)*D4 + o] : bp[(k0+1)*D4 + o];
    A2[t] = vg2 ? cp[(k0+2)*D4 + o] : bp[(k0+2)*D4 + o];
    A3[t] = vg3 ? cp[(k0+3)*D4 + o] : bp[(k0+3)*D4 + o];
  }
  float n0 = 0.f, n1 = 0.f, n2 = 0.f, n3 = 0.f;
#pragma unroll
  for (int t = 0; t < 3; ++t) {
    n0 += d4f(A0[t], A0[t]); n1 += d4f(A1[t], A1[t]);
    n2 += d4f(A2[t], A2[t]); n3 += d4f(A3[t], A3[t]);
  }
#pragma unroll
  for (int m = 1; m <= 32; m <<= 1) {
    n0 += __shfl_xor(n0, m); n1 += __shfl_xor(n1, m);
    n2 += __shfl_xor(n2, m); n3 += __shfl_xor(n3, m);
  }

  const long long ibase = (long long)chunk * C;
  for (int j = 0; j < C; ++j) {
    const long long i = ibase + j;
    const int lab = labels[i];
    const float4* vp = (const float4*)inputs + i * D4;
    float4 v0 = vp[l], v1 = vp[64 + l], v2 = vp[128 + l];

    float p0 = d4f(A0[0], v0) + d4f(A0[1], v1) + d4f(A0[2], v2);
    float p1 = d4f(A1[0], v0) + d4f(A1[1], v1) + d4f(A1[2], v2);
    float p2 = d4f(A2[0], v0) + d4f(A2[1], v1) + d4f(A2[2], v2);
    float p3 = d4f(A3[0], v0) + d4f(A3[1], v1) + d4f(A3[2], v2);
    float pv = d4f(v0, v0) + d4f(v1, v1) + d4f(v2, v2);
#pragma unroll
    for (int m = 1; m <= 32; m <<= 1) {
      p0 += __shfl_xor(p0, m); p1 += __shfl_xor(p1, m);
      p2 += __shfl_xor(p2, m); p3 += __shfl_xor(p3, m);
      pv += __shfl_xor(pv, m);
    }
    if (l < 4) {
      float ps = (l == 0) ? p0 : (l == 1) ? p1 : (l == 2) ? p2 : p3;
      float ns = (l == 0) ? n0 : (l == 1) ? n1 : (l == 2) ? n2 : n3;
      out[i * K + k0 + l] = ps * rsqrtf(fmaxf(ns * pv, 1e-30f));
    }
#define UPD(idx) do { \
      if (vg##idx) { A##idx[0]=v0; A##idx[1]=v1; A##idx[2]=v2; n##idx = pv; vg##idx = false; } \
      else { A##idx[0]=a4(A##idx[0],v0); A##idx[1]=a4(A##idx[1],v1); A##idx[2]=a4(A##idx[2],v2); \
             n##idx += 2.f * p##idx + pv; } } while (0)
    if      (lab == k0 + 0) UPD(0);
    else if (lab == k0 + 1) UPD(1);
    else if (lab == k0 + 2) UPD(2);
    else if (lab == k0 + 3) UPD(3);
#undef UPD
  }
}

// =====================================================================
extern "C" void kernel_launch(void* const* d_in, const int* in_sizes, int n_in,
                              void* d_out, int out_size, void* d_ws, size_t ws_size,
                              hipStream_t stream)
{
  const float* inputs = (const float*)d_in[0];
  const int*   labels = (const int*)d_in[1];
  const float* cavg   = (const float*)d_in[2];
  float* out = (float*)d_out;
  const int N = in_sizes[1];

  // Workspace layout for fast path
  const size_t szVb    = (size_t)32768 * D * 2;       // 50.3 MB bf16 inputs
  const size_t szSums  = (size_t)NCF * K * D * 4;     // 50.3 MB f32 chunk sums
  const size_t szSb16  = (size_t)NCF * K * D * 2;     // 25.2 MB bf16 scanned base
  const size_t szDot   = (size_t)32768 * 128 * 4;     // 16.8 MB dot buffer
  const size_t szAux   = (size_t)16 * K * D * 4;      // 3.1 MB group totals
  const size_t szPv    = (size_t)32768 * 4;
  const size_t szBn2   = (size_t)NCF * K * 4;
  const size_t szCnt   = (size_t)K * NCF * 4;
  const size_t szCavgb = (size_t)K * D * 2;
  const size_t szCn2   = (size_t)K * 4;
  size_t need = szVb + szSums + szSb16 + szDot + szAux + szPv + szBn2 + szCnt + szCavgb + szCn2 + 10 * 256;

  if (N == 32768 && in_sizes[2] == K * D && ws_size >= need) {
    char* p = (char*)d_ws;
    auto take = [&](size_t b) { char* r = p; p += (b + 255) & ~(size_t)255; return r; };
    unsigned short* Vb    = (unsigned short*)take(szVb);
    float*          sums  = (float*)take(szSums);
    unsigned short* Sb16  = (unsigned short*)take(szSb16);
    float*          dotb  = (float*)take(szDot);
    float*          aux   = (float*)take(szAux);
    float*          pv    = (float*)take(szPv);
    float*          bn2   = (float*)take(szBn2);
    int*            cnts  = (int*)take(szCnt);
    unsigned short* cavgb = (unsigned short*)take(szCavgb);
    float*          cn2   = (float*)take(szCn2);

    hipLaunchKernelGGL(k1_cast, dim3((N + K + 3) / 4), dim3(256), 0, stream,
                       inputs, cavg, Vb, cavgb, pv, cn2, N);
    hipLaunchKernelGGL(k2_chunk_sums, dim3(NCF * 12), dim3(256), 0, stream,
                       inputs, labels, sums, cnts, NCF, CF);
    hipLaunchKernelGGL(k2b_scan_cnts, dim3(1), dim3(K), 0, stream, cnts, NCF);
    hipLaunchKernelGGL(k3a_scan_lo, dim3(16 * 192), dim3(256), 0, stream, sums, aux);
    hipLaunchKernelGGL(k3b_scan_hi, dim3(192), dim3(256), 0, stream, aux);
    hipLaunchKernelGGL(k3c_finalize, dim3(NCF * 16), dim3(256), 0, stream,
                       sums, aux, Sb16, bn2);
    hipLaunchKernelGGL(k4_gemm, dim3(NCF), dim3(256), 0, stream,
                       Vb, Sb16, cavgb, labels, dotb);
    hipLaunchKernelGGL(k5_epilogue, dim3(NCF), dim3(K), 0, stream,
                       dotb, pv, labels, cnts, bn2, cn2, out, NCF);
    return;
  }

  // ---------------- fallback: round-1 pipeline ----------------
  int NC = 256;
  while (NC > 1) {
    size_t nd = (size_t)NC * K * D * 4 + (size_t)NC * K * 4;
    if (nd <= ws_size && (N % (NC * 4)) == 0) break;
    NC >>= 1;
  }
  const int C = N / NC;
  float* d_sums = (float*)d_ws;
  int*   d_cnts = (int*)((char*)d_ws + (size_t)NC * K * D * 4);

  hipLaunchKernelGGL(ph1_chunk_sums, dim3(NC * 12), dim3(256), 0, stream,
                     inputs, labels, d_sums, d_cnts, NC, C);
  hipLaunchKernelGGL(ph2a_scan_sums, dim3((K * D) / 256), dim3(256), 0, stream,
                     d_sums, NC);
  hipLaunchKernelGGL(ph2b_scan_cnts, dim3(1), dim3(64), 0, stream,
                     d_cnts, NC);
  hipLaunchKernelGGL(ph3_scan, dim3(NC * 4), dim3(256), 0, stream,
                     inputs, labels, cavg, d_sums, d_cnts, out, NC, C);
}

// Round 3
// 154.776 us; speedup vs baseline: 2.6182x; 1.3977x over previous
//
#include <hip/hip_runtime.h>
#include <cstddef>

#define K 64
#define D 768
#define D4 192   // D/4

__device__ __forceinline__ float d4f(float4 a, float4 b) {
  return a.x*b.x + a.y*b.y + a.z*b.z + a.w*b.w;
}
__device__ __forceinline__ float4 a4(float4 a, float4 b) {
  return make_float4(a.x+b.x, a.y+b.y, a.z+b.z, a.w+b.w);
}
__device__ __forceinline__ unsigned short f2bf(float x) {
  unsigned int u = __float_as_uint(x);
  unsigned int r = (u + 0x7FFFu + ((u >> 16) & 1u)) >> 16;
  return (unsigned short)r;
}

typedef __attribute__((ext_vector_type(8)))  short bf16x8;
typedef __attribute__((ext_vector_type(16))) float f32x16;

// =====================================================================
// FAST PATH (N=32768, NC=256, C=128)
// =====================================================================
#define NCF 256
#define CF  128

// ---- K1: cast inputs+cavg to bf16, compute ||v||^2 (f32 exact) ----
__global__ __launch_bounds__(256) void k1_cast(
    const float* __restrict__ inputs, const float* __restrict__ cavg,
    unsigned short* __restrict__ Vb, unsigned short* __restrict__ cavgb,
    float* __restrict__ pv, float* __restrict__ cn2, int N)
{
  int wave = blockIdx.x * 4 + (threadIdx.x >> 6);
  int l = threadIdx.x & 63;
  if (wave >= N + K) return;
  const float* src = (wave < N) ? inputs + (size_t)wave * D : cavg + (size_t)(wave - N) * D;
  unsigned short* dst = (wave < N) ? Vb + (size_t)wave * D : cavgb + (size_t)(wave - N) * D;
  float sq = 0.f;
#pragma unroll
  for (int t = 0; t < 3; ++t) {
    float4 v = ((const float4*)src)[t * 64 + l];
    sq += v.x*v.x + v.y*v.y + v.z*v.z + v.w*v.w;
    ushort4 o; o.x = f2bf(v.x); o.y = f2bf(v.y); o.z = f2bf(v.z); o.w = f2bf(v.w);
    ((ushort4*)dst)[t * 64 + l] = o;
  }
#pragma unroll
  for (int m = 1; m <= 32; m <<= 1) sq += __shfl_xor(sq, m);
  if (l == 0) { if (wave < N) pv[wave] = sq; else cn2[wave - N] = sq; }
}

// ---- K2: per-chunk per-class sums as MFMA GEMM: sums = Mt[64x128] @ V[128x768] ----
// A-frag: Mt rows (classes). B-frag: V^T assembled via 8x ds_read_u16 from
// row-major V tile (LDT=260 -> 8-row half-wave offset = bank 16 -> conflict-free).
#define LDT 260   // V-tile row stride (bf16 elems), rows 8B-aligned
#define LDM 136   // Mt row stride
__global__ __launch_bounds__(256) void k2_mfma(
    const unsigned short* __restrict__ Vb, const int* __restrict__ labels,
    float* __restrict__ sums, int* __restrict__ cnts_t)
{
  __shared__ unsigned short Vt[128 * LDT];   // 66560 B
  __shared__ unsigned short Mt[64 * LDM];    // 17408 B
  const int m = blockIdx.x;
  const int tid = threadIdx.x;
  const int w = tid >> 6, l = tid & 63;
  const int r31 = l & 31, kh = l >> 5;

  // build one-hot transpose Mt[k][j]
  for (int e = tid; e < 64 * LDM / 2; e += 256) ((unsigned int*)Mt)[e] = 0u;
  __syncthreads();
  if (tid < 128) {
    int lab = labels[m * 128 + tid];
    Mt[lab * LDM + tid] = 0x3F80;   // 1.0bf16
  }
  __syncthreads();
  if (tid < 64) {
    int c = 0;
    for (int j = 0; j < 128; ++j) c += (Mt[tid * LDM + j] != 0);
    cnts_t[tid * NCF + m] = c;
  }

  f32x16 acc[2][2];
  for (int kd = 0; kd < 3; ++kd) {
#pragma unroll
    for (int ct = 0; ct < 2; ++ct)
#pragma unroll
      for (int ti = 0; ti < 2; ++ti) acc[ct][ti] = (f32x16){};
    __syncthreads();
    // stage V slice [128 rows][256 cols]
#pragma unroll
    for (int it = 0; it < 16; ++it) {
      int flat = it * 256 + tid;          // uint4 id
      int row = flat >> 5, c16 = flat & 31;
      uint4 v = *(const uint4*)(Vb + ((size_t)(m * 128 + row)) * D + kd * 256 + c16 * 8);
      *(uint2*)(Vt + row * LDT + c16 * 8)     = make_uint2(v.x, v.y);
      *(uint2*)(Vt + row * LDT + c16 * 8 + 4) = make_uint2(v.z, v.w);
    }
    __syncthreads();
#pragma unroll
    for (int kk = 0; kk < 8; ++kk) {
      bf16x8 a0 = *(const bf16x8*)(Mt + (r31) * LDM + kk * 16 + kh * 8);
      bf16x8 a1 = *(const bf16x8*)(Mt + (32 + r31) * LDM + kk * 16 + kh * 8);
#pragma unroll
      for (int ti = 0; ti < 2; ++ti) {
        int td = w + ti * 4;
        bf16x8 b;
#pragma unroll
        for (int r = 0; r < 8; ++r)
          b[r] = *(const short*)(Vt + (kk * 16 + kh * 8 + r) * LDT + td * 32 + r31);
        acc[0][ti] = __builtin_amdgcn_mfma_f32_32x32x16_bf16(a0, b, acc[0][ti], 0, 0, 0);
        acc[1][ti] = __builtin_amdgcn_mfma_f32_32x32x16_bf16(a1, b, acc[1][ti], 0, 0, 0);
      }
    }
    // write this kd slab: C[class][d]
    float* sp = sums + (size_t)m * (K * D) + kd * 256;
#pragma unroll
    for (int ct = 0; ct < 2; ++ct)
#pragma unroll
      for (int ti = 0; ti < 2; ++ti) {
        int td = w + ti * 4;
#pragma unroll
        for (int q = 0; q < 16; ++q) {
          int kcls = ct * 32 + (q & 3) + 8 * (q >> 2) + 4 * kh;
          sp[(size_t)kcls * D + td * 32 + r31] = acc[ct][ti][q];
        }
      }
  }
}

// ---- K2b: exclusive scan of transposed counts ----
__global__ void k2b_scan_cnts(int* __restrict__ cnts_t, int NC)
{
  int k = threadIdx.x;
  int run = 0;
  int* p = cnts_t + k * NC;
  for (int m = 0; m < NC; ++m) { int t = p[m]; p[m] = run; run += t; }
}

// ---- K3a: level-1 exclusive scan (16 chunks per group, in place) + group totals ----
__global__ __launch_bounds__(256) void k3a_scan_lo(float* __restrict__ sums, float* __restrict__ aux)
{
  int g   = blockIdx.x / 192;
  int col = (blockIdx.x % 192) * 256 + threadIdx.x;
  float run = 0.f;
  for (int m = g * 16; m < g * 16 + 16; ++m) {
    size_t idx = (size_t)m * (K * D) + col;
    float t = sums[idx]; sums[idx] = run; run += t;
  }
  aux[(size_t)g * (K * D) + col] = run;
}

// ---- K3b: scan group totals ----
__global__ __launch_bounds__(256) void k3b_scan_hi(float* __restrict__ aux)
{
  int col = blockIdx.x * 256 + threadIdx.x;
  float run = 0.f;
  for (int g = 0; g < 16; ++g) {
    size_t idx = (size_t)g * (K * D) + col;
    float t = aux[idx]; aux[idx] = run; run += t;
  }
}

// ---- K3c: base = sums + aux -> bf16 rows + exact f32 row norms ----
__global__ __launch_bounds__(256) void k3c_finalize(
    const float* __restrict__ sums, const float* __restrict__ aux,
    unsigned short* __restrict__ Sb16, float* __restrict__ bn2)
{
  int m = blockIdx.x >> 4, rb = blockIdx.x & 15;
  int w = threadIdx.x >> 6, l = threadIdx.x & 63;
  int k = rb * 4 + w;
  const float4* sp = (const float4*)(sums + ((size_t)m * K + k) * D);
  const float4* ap = (const float4*)(aux + (size_t)(m >> 4) * (K * D) + (size_t)k * D);
  unsigned short* dp = Sb16 + ((size_t)m * K + k) * D;
  float sq = 0.f;
#pragma unroll
  for (int t = 0; t < 3; ++t) {
    float4 s = sp[t * 64 + l], a = ap[t * 64 + l];
    float4 b = make_float4(s.x + a.x, s.y + a.y, s.z + a.z, s.w + a.w);
    sq += b.x*b.x + b.y*b.y + b.z*b.z + b.w*b.w;
    ushort4 o; o.x = f2bf(b.x); o.y = f2bf(b.y); o.z = f2bf(b.z); o.w = f2bf(b.w);
    ((ushort4*)dp)[t * 64 + l] = o;
  }
#pragma unroll
  for (int mm = 1; mm <= 32; mm <<= 1) sq += __shfl_xor(sq, mm);
  if (l == 0) bn2[m * K + k] = sq;
}

// ---- K4: per-chunk fused GEMMs ----
#define LDV 264
#define LDS2 136
__global__ __launch_bounds__(256) void k4_gemm(
    const unsigned short* __restrict__ Vb, const unsigned short* __restrict__ Sb16,
    const unsigned short* __restrict__ cavgb, const int* __restrict__ labels,
    float* __restrict__ dotbuf)
{
  __shared__ unsigned short bufV[128 * LDV];
  __shared__ unsigned short bufB[128 * LDV];
  const int m = blockIdx.x;
  const int tid = threadIdx.x, w = tid >> 6, l = tid & 63;
  const int r31 = l & 31, kh = l >> 5;

  f32x16 accP[4], accS[4];
#pragma unroll
  for (int t = 0; t < 4; ++t) { accP[t] = (f32x16){}; accS[t] = (f32x16){}; }

  for (int kd = 0; kd < 3; ++kd) {
#pragma unroll 4
    for (int it = 0; it < 16; ++it) {
      int flat = it * 256 + tid;
      int row = flat >> 5, c16 = flat & 31;
      const unsigned short* sv = Vb + ((size_t)(m * 128 + row)) * D + kd * 256 + c16 * 8;
      *(uint4*)(bufV + row * LDV + c16 * 8) = *(const uint4*)sv;
      const unsigned short* sb = (row < 64)
          ? Sb16 + ((size_t)m * K + row) * D + kd * 256 + c16 * 8
          : cavgb + (size_t)(row - 64) * D + kd * 256 + c16 * 8;
      *(uint4*)(bufB + row * LDV + c16 * 8) = *(const uint4*)sb;
    }
    __syncthreads();
#pragma unroll 4
    for (int kk = 0; kk < 16; ++kk) {
      bf16x8 av = *(const bf16x8*)(bufV + (32 * w + r31) * LDV + kk * 16 + kh * 8);
#pragma unroll
      for (int t = 0; t < 4; ++t) {
        bf16x8 bB = *(const bf16x8*)(bufB + (32 * t + r31) * LDV + kk * 16 + kh * 8);
        accP[t] = __builtin_amdgcn_mfma_f32_32x32x16_bf16(av, bB, accP[t], 0, 0, 0);
        bf16x8 bV = *(const bf16x8*)(bufV + (32 * t + r31) * LDV + kk * 16 + kh * 8);
        accS[t] = __builtin_amdgcn_mfma_f32_32x32x16_bf16(av, bV, accS[t], 0, 0, 0);
      }
    }
    __syncthreads();
  }

  unsigned short* ldsS = bufB;
  unsigned short* Mt   = bufB + 128 * LDS2;
#pragma unroll
  for (int t = 0; t < 4; ++t)
#pragma unroll
    for (int q = 0; q < 16; ++q) {
      int i = 32 * w + (q & 3) + 8 * (q >> 2) + 4 * kh;
      int j = 32 * t + r31;
      ldsS[i * LDS2 + j] = (j < i) ? f2bf(accS[t][q]) : (unsigned short)0;
    }
  {
    int j = tid & 127;
    int lab = labels[m * 128 + j];
    int kbase = (tid >> 7) * 32;
#pragma unroll 8
    for (int kk = 0; kk < 32; ++kk) {
      int k = kbase + kk;
      Mt[k * LDS2 + j] = (lab == k) ? (unsigned short)0x3F80 : (unsigned short)0;
    }
  }
  __syncthreads();

#pragma unroll 2
  for (int kk = 0; kk < 8; ++kk) {
    bf16x8 aS = *(const bf16x8*)(ldsS + (32 * w + r31) * LDS2 + kk * 16 + kh * 8);
    bf16x8 b0 = *(const bf16x8*)(Mt + (r31) * LDS2 + kk * 16 + kh * 8);
    bf16x8 b1 = *(const bf16x8*)(Mt + (32 + r31) * LDS2 + kk * 16 + kh * 8);
    accP[0] = __builtin_amdgcn_mfma_f32_32x32x16_bf16(aS, b0, accP[0], 0, 0, 0);
    accP[1] = __builtin_amdgcn_mfma_f32_32x32x16_bf16(aS, b1, accP[1], 0, 0, 0);
  }

#pragma unroll
  for (int t = 0; t < 4; ++t)
#pragma unroll
    for (int q = 0; q < 16; ++q) {
      int i = 32 * w + (q & 3) + 8 * (q >> 2) + 4 * kh;
      int col = 32 * t + r31;
      dotbuf[((size_t)m * 128 + i) * 128 + col] = accP[t][q];
    }
}

// ---- K5: per-chunk norm recurrence, batched loads (8 indep loads per 8 serial steps) ----
__global__ void k5_epilogue(
    const float* __restrict__ dotbuf, const float* __restrict__ pv,
    const int* __restrict__ labels, const int* __restrict__ cnts_t,
    const float* __restrict__ bn2, const float* __restrict__ cn2,
    float* __restrict__ out, int NC)
{
  int m = blockIdx.x;
  int k = threadIdx.x & 63;
  int cnt = cnts_t[k * NC + m];
  float n = bn2[m * K + k];
  float cnk = cn2[k];
  for (int jb = 0; jb < CF; jb += 8) {
    float dS[8], dC[8], pvv[8]; int lb[8];
#pragma unroll
    for (int r = 0; r < 8; ++r) {
      int i = m * CF + jb + r;
      dS[r]  = dotbuf[(size_t)i * 128 + k];
      dC[r]  = dotbuf[(size_t)i * 128 + 64 + k];
      pvv[r] = pv[i];
      lb[r]  = labels[i];
    }
#pragma unroll
    for (int r = 0; r < 8; ++r) {
      int i = m * CF + jb + r;
      bool seen = cnt > 0;
      float val = seen ? dS[r] : dC[r];
      float nn  = seen ? n : cnk;
      out[(size_t)i * K + k] = val * rsqrtf(fmaxf(nn * pvv[r], 1e-30f));
      if (k == lb[r]) { n = seen ? (n + 2.f * dS[r] + pvv[r]) : pvv[r]; cnt++; }
    }
  }
}

// =====================================================================
// FALLBACK PATH — round-1 pipeline, verbatim (known-correct)
// =====================================================================
__global__ __launch_bounds__(256) void ph1_chunk_sums(
    const float* __restrict__ inputs, const int* __restrict__ labels,
    float* __restrict__ sums, int* __restrict__ cnts, int NC, int C)
{
  __shared__ float acc[4 * K * 64];
  __shared__ int   hist[4 * K];
  const int bi    = blockIdx.x;
  const int chunk = bi / 12, slice = bi % 12;
  const int w = threadIdx.x >> 6, l = threadIdx.x & 63;

  for (int e = threadIdx.x; e < 4 * K * 64; e += 256) acc[e] = 0.f;
  hist[threadIdx.x] = 0;
  __syncthreads();

  const int C4 = C >> 2;
  const long long rbase = (long long)chunk * C + (long long)w * C4;
  float* accw = acc + w * (K * 64);
  for (int j = 0; j < C4; ++j) {
    long long r = rbase + j;
    int lab = labels[r];
    float v = inputs[r * D + slice * 64 + l];
    accw[lab * 64 + l] += v;
    if (slice == 0 && l == 0) hist[w * K + lab]++;
  }
  __syncthreads();

  float* sp = sums + (long long)chunk * (K * D) + slice * 64;
  for (int e = threadIdx.x; e < K * 64; e += 256) {
    int k = e >> 6, dl = e & 63;
    float s = acc[0*K*64 + e] + acc[1*K*64 + e] + acc[2*K*64 + e] + acc[3*K*64 + e];
    sp[k * D + dl] = s;
  }
  if (slice == 0 && threadIdx.x < K) {
    cnts[chunk * K + threadIdx.x] =
        hist[0*K + threadIdx.x] + hist[1*K + threadIdx.x] +
        hist[2*K + threadIdx.x] + hist[3*K + threadIdx.x];
  }
}

__global__ __launch_bounds__(256) void ph2a_scan_sums(float* __restrict__ sums, int NC)
{
  const int tid = blockIdx.x * 256 + threadIdx.x;
  float run = 0.f;
  for (int m = 0; m < NC; ++m) {
    long long idx = (long long)m * (K * D) + tid;
    float t = sums[idx];
    sums[idx] = run;
    run += t;
  }
}

__global__ void ph2b_scan_cnts(int* __restrict__ cnts, int NC)
{
  const int k = threadIdx.x;
  int run = 0;
  for (int m = 0; m < NC; ++m) {
    int t = cnts[m * K + k];
    cnts[m * K + k] = run;
    run += t;
  }
}

__global__ __launch_bounds__(256, 4) void ph3_scan(
    const float* __restrict__ inputs, const int* __restrict__ labels,
    const float* __restrict__ cavg, const float* __restrict__ base,
    const int* __restrict__ cnts, float* __restrict__ out, int NC, int C)
{
  const int bi = blockIdx.x;
  int chunk, quad;
  if (NC >= 8) {
    int xcd = bi & 7, slot = bi >> 3;
    chunk = xcd * (NC >> 3) + (slot >> 2);
    quad  = slot & 3;
  } else {
    chunk = bi >> 2; quad = bi & 3;
  }
  const int w = threadIdx.x >> 6, l = threadIdx.x & 63;
  const int k0 = (quad * 4 + w) * 4;

  const int cb = chunk * K + k0;
  bool vg0 = (cnts[cb+0] == 0), vg1 = (cnts[cb+1] == 0);
  bool vg2 = (cnts[cb+2] == 0), vg3 = (cnts[cb+3] == 0);

  const float4* bp = (const float4*)base + (long long)chunk * (K * D4);
  const float4* cp = (const float4*)cavg;

  float4 A0[3], A1[3], A2[3], A3[3];
#pragma unroll
  for (int t = 0; t < 3; ++t) {
    int o = t * 64 + l;
    A0[t] = vg0 ? cp[(k0+0)*D4 + o] : bp[(k0+0)*D4 + o];
    A1[t] = vg1 ? cp[(k0+1)*D4 + o] : bp[(k0+1)*D4 + o];
    A2[t] = vg2 ? cp[(k0+2)*D4 + o] : bp[(k0+2)*D4 + o];
    A3[t] = vg3 ? cp[(k0+3)*D4 + o] : bp[(k0+3)*D4 + o];
  }
  float n0 = 0.f, n1 = 0.f, n2 = 0.f, n3 = 0.f;
#pragma unroll
  for (int t = 0; t < 3; ++t) {
    n0 += d4f(A0[t], A0[t]); n1 += d4f(A1[t], A1[t]);
    n2 += d4f(A2[t], A2[t]); n3 += d4f(A3[t], A3[t]);
  }
#pragma unroll
  for (int m = 1; m <= 32; m <<= 1) {
    n0 += __shfl_xor(n0, m); n1 += __shfl_xor(n1, m);
    n2 += __shfl_xor(n2, m); n3 += __shfl_xor(n3, m);
  }

  const long long ibase = (long long)chunk * C;
  for (int j = 0; j < C; ++j) {
    const long long i = ibase + j;
    const int lab = labels[i];
    const float4* vp = (const float4*)inputs + i * D4;
    float4 v0 = vp[l], v1 = vp[64 + l], v2 = vp[128 + l];

    float p0 = d4f(A0[0], v0) + d4f(A0[1], v1) + d4f(A0[2], v2);
    float p1 = d4f(A1[0], v0) + d4f(A1[1], v1) + d4f(A1[2], v2);
    float p2 = d4f(A2[0], v0) + d4f(A2[1], v1) + d4f(A2[2], v2);
    float p3 = d4f(A3[0], v0) + d4f(A3[1], v1) + d4f(A3[2], v2);
    float pv = d4f(v0, v0) + d4f(v1, v1) + d4f(v2, v2);
#pragma unroll
    for (int m = 1; m <= 32; m <<= 1) {
      p0 += __shfl_xor(p0, m); p1 += __shfl_xor(p1, m);
      p2 += __shfl_xor(p2, m); p3 += __shfl_xor(p3, m);
      pv += __shfl_xor(pv, m);
    }
    if (l < 4) {
      float ps = (l == 0) ? p0 : (l == 1) ? p1 : (l == 2) ? p2 : p3;
      float ns = (l == 0) ? n0 : (l == 1) ? n1 : (l == 2) ? n2 : n3;
      out[i * K + k0 + l] = ps * rsqrtf(fmaxf(ns * pv, 1e-30f));
    }
#define UPD(idx) do { \
      if (vg##idx) { A##idx[0]=v0; A##idx[1]=v1; A##idx[2]=v2; n##idx = pv; vg##idx = false; } \
      else { A##idx[0]=a4(A##idx[0],v0); A##idx[1]=a4(A##idx[1],v1); A##idx[2]=a4(A##idx[2],v2); \
             n##idx += 2.f * p##idx + pv; } } while (0)
    if      (lab == k0 + 0) UPD(0);
    else if (lab == k0 + 1) UPD(1);
    else if (lab == k0 + 2) UPD(2);
    else if (lab == k0 + 3) UPD(3);
#undef UPD
  }
}

// =====================================================================
extern "C" void kernel_launch(void* const* d_in, const int* in_sizes, int n_in,
                              void* d_out, int out_size, void* d_ws, size_t ws_size,
                              hipStream_t stream)
{
  const float* inputs = (const float*)d_in[0];
  const int*   labels = (const int*)d_in[1];
  const float* cavg   = (const float*)d_in[2];
  float* out = (float*)d_out;
  const int N = in_sizes[1];

  const size_t szVb    = (size_t)32768 * D * 2;
  const size_t szSums  = (size_t)NCF * K * D * 4;
  const size_t szSb16  = (size_t)NCF * K * D * 2;
  const size_t szDot   = (size_t)32768 * 128 * 4;
  const size_t szAux   = (size_t)16 * K * D * 4;
  const size_t szPv    = (size_t)32768 * 4;
  const size_t szBn2   = (size_t)NCF * K * 4;
  const size_t szCnt   = (size_t)K * NCF * 4;
  const size_t szCavgb = (size_t)K * D * 2;
  const size_t szCn2   = (size_t)K * 4;
  size_t need = szVb + szSums + szSb16 + szDot + szAux + szPv + szBn2 + szCnt + szCavgb + szCn2 + 10 * 256;

  if (N == 32768 && in_sizes[2] == K * D && ws_size >= need) {
    char* p = (char*)d_ws;
    auto take = [&](size_t b) { char* r = p; p += (b + 255) & ~(size_t)255; return r; };
    unsigned short* Vb    = (unsigned short*)take(szVb);
    float*          sums  = (float*)take(szSums);
    unsigned short* Sb16  = (unsigned short*)take(szSb16);
    float*          dotb  = (float*)take(szDot);
    float*          aux   = (float*)take(szAux);
    float*          pv    = (float*)take(szPv);
    float*          bn2   = (float*)take(szBn2);
    int*            cnts  = (int*)take(szCnt);
    unsigned short* cavgb = (unsigned short*)take(szCavgb);
    float*          cn2   = (float*)take(szCn2);

    hipLaunchKernelGGL(k1_cast, dim3((N + K + 3) / 4), dim3(256), 0, stream,
                       inputs, cavg, Vb, cavgb, pv, cn2, N);
    hipLaunchKernelGGL(k2_mfma, dim3(NCF), dim3(256), 0, stream,
                       Vb, labels, sums, cnts);
    hipLaunchKernelGGL(k2b_scan_cnts, dim3(1), dim3(K), 0, stream, cnts, NCF);
    hipLaunchKernelGGL(k3a_scan_lo, dim3(16 * 192), dim3(256), 0, stream, sums, aux);
    hipLaunchKernelGGL(k3b_scan_hi, dim3(192), dim3(256), 0, stream, aux);
    hipLaunchKernelGGL(k3c_finalize, dim3(NCF * 16), dim3(256), 0, stream,
                       sums, aux, Sb16, bn2);
    hipLaunchKernelGGL(k4_gemm, dim3(NCF), dim3(256), 0, stream,
                       Vb, Sb16, cavgb, labels, dotb);
    hipLaunchKernelGGL(k5_epilogue, dim3(NCF), dim3(K), 0, stream,
                       dotb, pv, labels, cnts, bn2, cn2, out, NCF);
    return;
  }

  // ---------------- fallback: round-1 pipeline ----------------
  int NC = 256;
  while (NC > 1) {
    size_t nd = (size_t)NC * K * D * 4 + (size_t)NC * K * 4;
    if (nd <= ws_size && (N % (NC * 4)) == 0) break;
    NC >>= 1;
  }
  const int C = N / NC;
  float* d_sums = (float*)d_ws;
  int*   d_cnts = (int*)((char*)d_ws + (size_t)NC * K * D * 4);

  hipLaunchKernelGGL(ph1_chunk_sums, dim3(NC * 12), dim3(256), 0, stream,
                     inputs, labels, d_sums, d_cnts, NC, C);
  hipLaunchKernelGGL(ph2a_scan_sums, dim3((K * D) / 256), dim3(256), 0, stream,
                     d_sums, NC);
  hipLaunchKernelGGL(ph2b_scan_cnts, dim3(1), dim3(64), 0, stream,
                     d_cnts, NC);
  hipLaunchKernelGGL(ph3_scan, dim3(NC * 4), dim3(256), 0, stream,
                     inputs, labels, cavg, d_sums, d_cnts, out, NC, C);
}